// Round 2
// baseline (1116.306 us; speedup 1.0000x reference)
//
#include <hip/hip_runtime.h>

#define NODES 25088
#define NB 8
#define NPB 3136   // nodes per batch (56*56)
#define C 96
#define KNN 9
#define COUT 192

// ---------------- transpose x [B,C,N] -> xf [B*N, C] ----------------
__global__ void transpose_kernel(const float* __restrict__ x, float* __restrict__ xf) {
  __shared__ float t[32][33];
  int b = blockIdx.z, ct = blockIdx.y, nt = blockIdx.x;
  int tx = threadIdx.x, ty = threadIdx.y;
  int n0 = nt * 32, c0 = ct * 32;
  const float* xb = x + (size_t)b * C * NPB;
#pragma unroll
  for (int i = 0; i < 4; i++) {
    int c = c0 + ty + i * 8;
    t[ty + i * 8][tx] = xb[(size_t)c * NPB + n0 + tx];
  }
  __syncthreads();
  float* xfb = xf + (size_t)b * NPB * C;
#pragma unroll
  for (int i = 0; i < 4; i++) {
    int n = n0 + ty + i * 8;
    xfb[(size_t)n * C + c0 + tx] = t[tx][ty + i * 8];
  }
}

// ---------------- per-node squared norm ----------------
__global__ void sq_kernel(const float* __restrict__ xf, float* __restrict__ sq) {
  int node = blockIdx.x * 256 + threadIdx.x;
  const float4* r = (const float4*)(xf + (size_t)node * C);
  float s = 0.f;
#pragma unroll
  for (int i = 0; i < 24; i++) {
    float4 v = r[i];
    s += v.x * v.x + v.y * v.y + v.z * v.z + v.w * v.w;
  }
  sq[node] = s;
}

// ---------------- kNN: top-9 smallest distances per row ----------------
// grid (49, 8), block 256 (4 waves). Each block: 64 query rows.
__global__ __launch_bounds__(256) void knn_kernel(const float* __restrict__ xf,
                                                  const float* __restrict__ sq,
                                                  int* __restrict__ nn) {
  __shared__ float tile[64 * C];  // 24576 B
  __shared__ float sqs[64];
  int b = blockIdx.y;
  int lane = threadIdx.x & 63;
  int sub = threadIdx.x >> 6;
  int row = blockIdx.x * 64 + lane;
  int bbase = b * NPB;

  float4 r4[24];
  const float4* rp = (const float4*)(xf + (size_t)(bbase + row) * C);
#pragma unroll
  for (int i = 0; i < 24; i++) r4[i] = rp[i];
  float sqr = sq[bbase + row];

  float nd[KNN];
  int ni[KNN];
#pragma unroll
  for (int q = 0; q < KNN; q++) { nd[q] = 3.4e38f; ni[q] = 0; }

  for (int t = 0; t < NPB / 64; t++) {
    int m0 = t * 64;
    __syncthreads();
    for (int f = threadIdx.x; f < 64 * 24; f += 256) {
      int mr = f / 24, c4 = f % 24;
      ((float4*)tile)[mr * 24 + c4] =
          ((const float4*)(xf + (size_t)(bbase + m0 + mr) * C))[c4];
    }
    if (threadIdx.x < 64) sqs[threadIdx.x] = sq[bbase + m0 + threadIdx.x];
    __syncthreads();
    for (int q = 0; q < 16; q++) {
      int mr = sub * 16 + q;
      const float4* mp = (const float4*)(tile + mr * C);
      float d0 = 0.f, d1 = 0.f, d2 = 0.f, d3 = 0.f;
#pragma unroll
      for (int i = 0; i < 24; i++) {
        float4 mv = mp[i];
        d0 += r4[i].x * mv.x;
        d1 += r4[i].y * mv.y;
        d2 += r4[i].z * mv.z;
        d3 += r4[i].w * mv.w;
      }
      float dot = (d0 + d1) + (d2 + d3);
      float d = (sqr - 2.0f * dot) + sqs[mr];
      int m = m0 + mr;
      if (d < nd[KNN - 1]) {
        nd[KNN - 1] = d;
        ni[KNN - 1] = m;
#pragma unroll
        for (int qq = KNN - 1; qq > 0; --qq) {
          if (nd[qq] < nd[qq - 1]) {
            float td = nd[qq]; nd[qq] = nd[qq - 1]; nd[qq - 1] = td;
            int ti = ni[qq]; ni[qq] = ni[qq - 1]; ni[qq - 1] = ti;
          }
        }
      }
    }
  }

  __syncthreads();
  float* cd = tile;                    // 4*64*9 floats
  int* ci = (int*)(tile + 4 * 64 * KNN);
#pragma unroll
  for (int q = 0; q < KNN; q++) {
    cd[(sub * 64 + lane) * KNN + q] = nd[q];
    ci[(sub * 64 + lane) * KNN + q] = ni[q];
  }
  __syncthreads();
  if (sub == 0) {
    float fd[KNN];
    int fi[KNN];
#pragma unroll
    for (int q = 0; q < KNN; q++) { fd[q] = 3.4e38f; fi[q] = 0x7fffffff; }
    for (int s = 0; s < 4; s++) {
#pragma unroll
      for (int q = 0; q < KNN; q++) {
        float d = cd[(s * 64 + lane) * KNN + q];
        int m = ci[(s * 64 + lane) * KNN + q];
        if (d < fd[KNN - 1] || (d == fd[KNN - 1] && m < fi[KNN - 1])) {
          fd[KNN - 1] = d;
          fi[KNN - 1] = m;
#pragma unroll
          for (int qq = KNN - 1; qq > 0; --qq) {
            bool sw = (fd[qq] < fd[qq - 1]) ||
                      (fd[qq] == fd[qq - 1] && fi[qq] < fi[qq - 1]);
            if (sw) {
              float td = fd[qq]; fd[qq] = fd[qq - 1]; fd[qq - 1] = td;
              int ti = fi[qq]; fi[qq] = fi[qq - 1]; fi[qq - 1] = ti;
            }
          }
        }
      }
    }
#pragma unroll
    for (int q = 0; q < KNN; q++)
      nn[(size_t)(bbase + row) * KNN + q] = bbase + fi[q];
  }
}

// ---------------- fused VAE tail: hK[500] -> 64 -> 32 -> 9 -> argmax ----------------
__global__ void vae_tail_kernel(const float* __restrict__ hK,
                                const float* __restrict__ kfc_w, const float* __restrict__ kfc_b,
                                const float* __restrict__ kmu_w, const float* __restrict__ kmu_b,
                                const float* __restrict__ kdec_w, const float* __restrict__ kdec_b,
                                int node_base, int* __restrict__ kint, float* __restrict__ rs) {
  __shared__ float hrow[8][500];
  __shared__ float h64s[8][64];
  __shared__ float mus[8][32];
  __shared__ float lg[8][9];
  int tid = threadIdx.x;
  int nb = blockIdx.x * 8;
  for (int f = tid; f < 8 * 500; f += 256) {
    int nl = f / 500, q = f % 500;
    hrow[nl][q] = hK[(size_t)(nb + nl) * 500 + q];
  }
  __syncthreads();
  {
    int nl0 = tid >> 6, j = tid & 63;
    float a0 = 0.f, a1 = 0.f;
    for (int q = 0; q < 500; q++) {
      float w = kfc_w[q * 64 + j];
      a0 += hrow[nl0][q] * w;
      a1 += hrow[nl0 + 4][q] * w;
    }
    float bj = kfc_b[j];
    h64s[nl0][j] = fmaxf(a0 + bj, 0.f);
    h64s[nl0 + 4][j] = fmaxf(a1 + bj, 0.f);
  }
  __syncthreads();
  {
    int nl = tid / 32, j = tid % 32;
    float a = 0.f;
#pragma unroll
    for (int q = 0; q < 64; q++) a += h64s[nl][q] * kmu_w[q * 32 + j];
    mus[nl][j] = a + kmu_b[j];
  }
  __syncthreads();
  if (tid < 72) {
    int nl = tid / 9, j = tid % 9;
    float a = 0.f;
#pragma unroll
    for (int q = 0; q < 32; q++) a += mus[nl][q] * kdec_w[q * 9 + j];
    lg[nl][j] = a + kdec_b[j];
  }
  __syncthreads();
  if (tid < 8) {
    float best = lg[tid][0];
    int bi = 0;
#pragma unroll
    for (int j = 1; j < 9; j++) {
      if (lg[tid][j] > best) { best = lg[tid][j]; bi = j; }
    }
    kint[node_base + nb + tid] = bi;
    rs[node_base + nb + tid] = (float)bi;
  }
}

// ---------------- gather-sum of kept neighbors ----------------
__global__ void gather_kernel(const float* __restrict__ feat, const int* __restrict__ nn,
                              const int* __restrict__ kint, float* __restrict__ out) {
  int idx = blockIdx.x * 256 + threadIdx.x;
  int node = idx / 24, c4 = idx % 24;
  int kc = kint[node];
  const int* nr = nn + (size_t)node * KNN;
  float4 acc = make_float4(0.f, 0.f, 0.f, 0.f);
  for (int k = 0; k < kc; k++) {
    int j = nr[k];
    float4 v = ((const float4*)(feat + (size_t)j * C))[c4];
    acc.x += v.x; acc.y += v.y; acc.z += v.z; acc.w += v.w;
  }
  ((float4*)(out + (size_t)node * C))[c4] = acc;
}

// ---------------- generic fp32 GEMM ----------------
// C[M,N] = [A0 (rowscale sc0) | A1 (rowscale sc1)] @ B' + bscale*bias, opt relu,
// opt transpose-store to [B, COUT, NPB]. bmode 1: B' rows k<96 are B[k]-B[k+96].
__global__ __launch_bounds__(256) void gemm_kernel(
    const float* __restrict__ A0, const float* __restrict__ A1, int K0, int Ktot,
    const float* __restrict__ sc0, const float* __restrict__ sc1,
    const float* __restrict__ B, int ldb, int bmode,
    const float* __restrict__ bias, const float* __restrict__ bscale,
    float* __restrict__ Cc, int M, int N, int relu, int tstore) {
  __shared__ float As[16][68];
  __shared__ float Bs[16][68];
  int tid = threadIdx.x;
  int tx = tid & 15, ty = tid >> 4;
  int row0 = blockIdx.x * 64, col0 = blockIdx.y * 64;
  float acc[4][4] = {};
  int ai = tid >> 2;          // 0..63
  int ak = (tid & 3) * 4;     // 0,4,8,12
  int bk = tid >> 4;          // 0..15
  int bj = (tid & 15) * 4;    // 0..60
  bool edge = (col0 + 64 > N);

  for (int k0 = 0; k0 < Ktot; k0 += 16) {
    // stage A (64 x 16), transposed into As[k][i]
    {
      const float* Ap;
      const float* sc;
      int lda, kk;
      if (k0 < K0) { Ap = A0; lda = K0; sc = sc0; kk = k0; }
      else { Ap = A1; lda = Ktot - K0; sc = sc1; kk = k0 - K0; }
      int r = row0 + ai;
      float4 v = *(const float4*)(Ap + (size_t)r * lda + kk + ak);
      if (sc) { float s = sc[r]; v.x *= s; v.y *= s; v.z *= s; v.w *= s; }
      As[ak + 0][ai] = v.x;
      As[ak + 1][ai] = v.y;
      As[ak + 2][ai] = v.z;
      As[ak + 3][ai] = v.w;
    }
    // stage B (16 x 64)
    {
      int kg = k0 + bk;
      int j = col0 + bj;
      float4 v;
      if (!edge) {
        v = *(const float4*)(B + (size_t)kg * ldb + j);
        if (bmode == 1 && kg < 96) {
          float4 w = *(const float4*)(B + (size_t)(kg + 96) * ldb + j);
          v.x -= w.x; v.y -= w.y; v.z -= w.z; v.w -= w.w;
        }
      } else {
        float tmp[4];
#pragma unroll
        for (int e = 0; e < 4; e++) {
          int jj = j + e;
          float val = 0.f;
          if (jj < N) {
            val = B[(size_t)kg * ldb + jj];
            if (bmode == 1 && kg < 96) val -= B[(size_t)(kg + 96) * ldb + jj];
          }
          tmp[e] = val;
        }
        v = make_float4(tmp[0], tmp[1], tmp[2], tmp[3]);
      }
      *(float4*)&Bs[bk][bj] = v;
    }
    __syncthreads();
#pragma unroll
    for (int kk = 0; kk < 16; kk++) {
      float4 av = *(const float4*)&As[kk][ty * 4];
      float4 bv = *(const float4*)&Bs[kk][tx * 4];
      acc[0][0] += av.x * bv.x; acc[0][1] += av.x * bv.y; acc[0][2] += av.x * bv.z; acc[0][3] += av.x * bv.w;
      acc[1][0] += av.y * bv.x; acc[1][1] += av.y * bv.y; acc[1][2] += av.y * bv.z; acc[1][3] += av.y * bv.w;
      acc[2][0] += av.z * bv.x; acc[2][1] += av.z * bv.y; acc[2][2] += av.z * bv.z; acc[2][3] += av.z * bv.w;
      acc[3][0] += av.w * bv.x; acc[3][1] += av.w * bv.y; acc[3][2] += av.w * bv.z; acc[3][3] += av.w * bv.w;
    }
    __syncthreads();
  }
#pragma unroll
  for (int ii = 0; ii < 4; ii++) {
    int r = row0 + ty * 4 + ii;
    float bsv = bscale ? bscale[r] : 1.f;
#pragma unroll
    for (int jj = 0; jj < 4; jj++) {
      int j = col0 + tx * 4 + jj;
      if (edge && j >= N) continue;
      float v = acc[ii][jj];
      if (bias) v += bsv * bias[j];
      if (relu) v = fmaxf(v, 0.f);
      if (tstore) {
        int bb = r / NPB, n = r % NPB;
        Cc[(size_t)bb * COUT * NPB + (size_t)j * NPB + n] = v;
      } else {
        Cc[(size_t)r * N + j] = v;
      }
    }
  }
}

extern "C" void kernel_launch(void* const* d_in, const int* in_sizes, int n_in,
                              void* d_out, int out_size, void* d_ws, size_t ws_size,
                              hipStream_t stream) {
  const float* x      = (const float*)d_in[0];
  const float* kmap_w = (const float*)d_in[1];
  const float* kmap_b = (const float*)d_in[2];
  const float* kfc_w  = (const float*)d_in[3];
  const float* kfc_b  = (const float*)d_in[4];
  const float* kmu_w  = (const float*)d_in[5];
  const float* kmu_b  = (const float*)d_in[6];
  const float* kdec_w = (const float*)d_in[7];
  const float* kdec_b = (const float*)d_in[8];
  const float* ec1_w  = (const float*)d_in[9];
  const float* ec1_b  = (const float*)d_in[10];
  const float* ec2_w  = (const float*)d_in[11];
  const float* ec2_b  = (const float*)d_in[12];
  const float* fc_w   = (const float*)d_in[13];
  const float* fc_b   = (const float*)d_in[14];
  const float* io_w   = (const float*)d_in[15];
  const float* io_b   = (const float*)d_in[16];
  const float* up_w   = (const float*)d_in[17];
  const float* up_b   = (const float*)d_in[18];

  // ---- workspace layout (liveness-aliased; total ~49.4 MB) ----
  char* ws = (char*)d_ws;
  size_t off = 0;
  auto alloc = [&](size_t bytes) -> void* {
    void* p = ws + off;
    off += (bytes + 255) & ~(size_t)255;
    return p;
  };
  float* xf    = (float*)alloc((size_t)NODES * C * 4);   // later reused as bufH2
  float* sqb   = (float*)alloc((size_t)NODES * 4);
  float* rs    = (float*)alloc((size_t)NODES * 4);
  int*   kint  = (int*)alloc((size_t)NODES * 4);
  int*   nn    = (int*)alloc((size_t)NODES * KNN * 4);
  float* bufH1 = (float*)alloc((size_t)NODES * C * 4);   // NODES*C*4 is 256-aligned
  float* bufS  = (float*)alloc((size_t)NODES * C * 4);   // contiguous after bufH1
  float* bufXio = (float*)alloc((size_t)NODES * COUT * 4);
  float* hK     = bufXio;  // 6272*500 floats < NODES*COUT; dead before xio written
  float* bufH2  = xf;      // xf dead after xio GEMM
  float* bufAgg = bufH1;   // spans bufH1+bufS (exactly NODES*COUT*4); both dead

  transpose_kernel<<<dim3(98, 3, 8), dim3(32, 8), 0, stream>>>(x, xf);
  sq_kernel<<<98, 256, 0, stream>>>(xf, sqb);

  // VAE head: 96->500 GEMM (M-chunked) + fused 500->64->32->9->argmax
  for (int c = 0; c < 4; c++) {
    gemm_kernel<<<dim3(98, 8), 256, 0, stream>>>(
        xf + (size_t)c * 6272 * C, nullptr, 96, 96, nullptr, nullptr,
        kmap_w, 500, 0, kmap_b, nullptr, hK, 6272, 500, 0, 0);
    vae_tail_kernel<<<784, 256, 0, stream>>>(hK, kfc_w, kfc_b, kmu_w, kmu_b,
                                             kdec_w, kdec_b, c * 6272, kint, rs);
  }

  knn_kernel<<<dim3(49, 8), 256, 0, stream>>>(xf, sqb, nn);

  // EdgeConv layer 1: h1 = relu(k*xi@(W1-W2) + S@W2 + k*b)
  gather_kernel<<<2352, 256, 0, stream>>>(xf, nn, kint, bufS);
  gemm_kernel<<<dim3(392, 2), 256, 0, stream>>>(
      xf, bufS, 96, 192, rs, nullptr, ec1_w, 96, 1, ec1_b, rs, bufH1, NODES, 96, 1, 0);

  // xio = nodes @ io_w + io_b  (before L2 so xf can be reused as bufH2)
  gemm_kernel<<<dim3(392, 3), 256, 0, stream>>>(
      xf, nullptr, 96, 96, nullptr, nullptr, io_w, COUT, 0, io_b, nullptr, bufXio, NODES, COUT, 0, 0);

  // EdgeConv layer 2 (no relu)
  gather_kernel<<<2352, 256, 0, stream>>>(bufH1, nn, kint, bufS);
  gemm_kernel<<<dim3(392, 2), 256, 0, stream>>>(
      bufH1, bufS, 96, 192, rs, nullptr, ec2_w, 96, 1, ec2_b, rs, bufH2, NODES, 96, 0, 0);

  // agg = h2 @ fc_w + fc_b
  gemm_kernel<<<dim3(392, 3), 256, 0, stream>>>(
      bufH2, nullptr, 96, 96, nullptr, nullptr, fc_w, COUT, 0, fc_b, nullptr, bufAgg, NODES, COUT, 0, 0);

  // final: relu([xio | agg] @ up_w + up_b), transpose-store to [B, 192, 3136]
  gemm_kernel<<<dim3(392, 3), 256, 0, stream>>>(
      bufXio, bufAgg, 192, 384, nullptr, nullptr, up_w, COUT, 0, up_b, nullptr,
      (float*)d_out, NODES, COUT, 1, 1);
}